// Round 8
// baseline (10302.236 us; speedup 1.0000x reference)
//
#include <hip/hip_runtime.h>
#include <hip/hip_bf16.h>

#define S_LEN 256
#define BATCH 64
#define EMB   300
#define EPAD  304
#define HID   512
#define G4H   2048
#define NCLS  25
#define TWOH  1024

using bf16 = __hip_bfloat16;
typedef short bf8v __attribute__((ext_vector_type(8)));   // 8 bf16 in 4 VGPRs
typedef float f32x4 __attribute__((ext_vector_type(4)));
typedef unsigned long long ull;

__device__ __forceinline__ float us2f(unsigned short u) {
    union { unsigned int i; float f; } v; v.i = ((unsigned int)u) << 16; return v.f;
}
__device__ __forceinline__ float sigm(float x) { return 1.f / (1.f + __expf(-x)); }

// ---------------- embedding gather: x[t][b][e] (bf16, padded to EPAD) ----------------
__global__ void embed_kernel(const int* __restrict__ ids,
                             const float* __restrict__ emb,
                             bf16* __restrict__ x)
{
    int r = blockIdx.x;            // r = t*BATCH + b
    int t = r >> 6, b = r & 63;
    int id = ids[b * S_LEN + t];
    const float* src = emb + (size_t)id * EMB;
    bf16* dst = x + (size_t)r * EPAD;
    for (int e = threadIdx.x; e < EPAD; e += blockDim.x) {
        float v = (e < EMB) ? src[e] : 0.f;
        dst[e] = __float2bfloat16(v);
    }
}

// ------- transpose recurrent weights to bf16: whTb[wl][u][g][k] = W[D+k][g*512+u] -------
__global__ void wtrans_kernel(const float* __restrict__ w_fw0, const float* __restrict__ w_bw0,
                              const float* __restrict__ w_fw1, const float* __restrict__ w_bw1,
                              bf16* __restrict__ whTb)
{
    __shared__ float tile[32][33];
    int wl = blockIdx.z;
    const float* W; int D;
    if (wl == 0)      { W = w_fw0; D = EMB; }
    else if (wl == 1) { W = w_bw0; D = EMB; }
    else if (wl == 2) { W = w_fw1; D = TWOH; }
    else              { W = w_bw1; D = TWOH; }
    int k0 = blockIdx.x * 32, n0 = blockIdx.y * 32;
    int tx = threadIdx.x, ty = threadIdx.y;
    tile[ty][tx] = W[(size_t)(D + k0 + ty) * G4H + n0 + tx];
    __syncthreads();
    int k = k0 + tx;
    int n = n0 + ty;                  // gate-major column index
    int u = n & 511, g = n >> 9;
    whTb[(((size_t)wl * 512 + u) * 4 + g) * 512 + k] = __float2bfloat16(tile[tx][ty]);
}

// -------- input-gate precompute GEMM: Gt[z][t][n][b] = (gather(A) @ Wx + bias)^T --------
__global__ __launch_bounds__(256)
void gates_gemm(const bf16* __restrict__ A, int strideA, int Keff,
                const float* __restrict__ W_fw, const float* __restrict__ W_bw,
                const float* __restrict__ b_fw, const float* __restrict__ b_bw,
                const int* __restrict__ lengths,
                bf16* __restrict__ Gt)
{
    const int z = blockIdx.z;
    const float* W    = z ? W_bw : W_fw;
    const float* bias = z ? b_bw : b_fw;
    const int m0 = blockIdx.x * 128;
    const int n0 = blockIdx.y * 128;
    const int tid = threadIdx.x;

    __shared__ __align__(16) float As[16][132];
    __shared__ __align__(16) float Bs[16][132];

    const int row_l = tid >> 1;
    const int kseg  = (tid & 1) * 8;
    int r = m0 + row_l;
    int t = r >> 6, b = r & 63;
    int st = t;
    if (z) { int len = lengths[b]; st = (t < len) ? (len - 1 - t) : t; }
    const bf16* arow = A + (size_t)(st * BATCH + b) * strideA + kseg;

    const int krow = tid >> 4;
    const int nseg = (tid & 15) * 8;
    const float* brow = W + (size_t)krow * G4H + n0 + nseg;

    const int ty = tid >> 4, tx = tid & 15;
    const int mt = ty * 8, nt = tx * 8;

    float acc[8][8];
#pragma unroll
    for (int i = 0; i < 8; ++i)
#pragma unroll
        for (int j = 0; j < 8; ++j) acc[i][j] = 0.f;

    for (int kt = 0; kt < Keff; kt += 16) {
        uint4 av = *reinterpret_cast<const uint4*>(arow + kt);
        const unsigned short* as8 = reinterpret_cast<const unsigned short*>(&av);
        float4 bld0 = *reinterpret_cast<const float4*>(brow + (size_t)kt * G4H);
        float4 bld1 = *reinterpret_cast<const float4*>(brow + (size_t)kt * G4H + 4);
#pragma unroll
        for (int j = 0; j < 8; ++j) As[kseg + j][row_l] = us2f(as8[j]);
        *reinterpret_cast<float4*>(&Bs[krow][nseg])     = bld0;
        *reinterpret_cast<float4*>(&Bs[krow][nseg + 4]) = bld1;
        __syncthreads();
#pragma unroll
        for (int k = 0; k < 16; ++k) {
            float4 a0 = *reinterpret_cast<const float4*>(&As[k][mt]);
            float4 a1 = *reinterpret_cast<const float4*>(&As[k][mt + 4]);
            float4 c0 = *reinterpret_cast<const float4*>(&Bs[k][nt]);
            float4 c1 = *reinterpret_cast<const float4*>(&Bs[k][nt + 4]);
            float a8[8] = {a0.x,a0.y,a0.z,a0.w,a1.x,a1.y,a1.z,a1.w};
            float b8[8] = {c0.x,c0.y,c0.z,c0.w,c1.x,c1.y,c1.z,c1.w};
#pragma unroll
            for (int i = 0; i < 8; ++i)
#pragma unroll
                for (int j = 0; j < 8; ++j)
                    acc[i][j] = fmaf(a8[i], b8[j], acc[i][j]);
        }
        __syncthreads();
    }

    // epilogue: Gt[z][t][n][b] — i spans 8 consecutive b within one t (mt multiple of 8)
    const int t_ = (m0 + mt) >> 6;
    const int b0 = (m0 + mt) & 63;
#pragma unroll
    for (int j = 0; j < 8; ++j) {
        float bvj = bias[n0 + nt + j];
        __align__(16) bf16 tmp[8];
#pragma unroll
        for (int i = 0; i < 8; ++i) tmp[i] = __float2bfloat16(acc[i][j] + bvj);
        bf16* gout = Gt + (((size_t)z * S_LEN + t_) * G4H + (n0 + nt + j)) * BATCH + b0;
        *reinterpret_cast<uint4*>(gout) = *reinterpret_cast<const uint4*>(tmp);
    }
}

// ---------------- persistent MFMA LSTM recurrence — SELF-TIMED DATAFLOW ----------------
// 32 blocks = 2 dirs x 16 u-tiles. Weights persistent in VGPR B-frags (as R7).
// NO barrier, NO flags, NO vmcnt drain: hseq[t][d][b][u] is slot-per-timestep (never
// reused -> no WAR), pre-memset to 0xFFFF (bf16 NaN, unreachable as real h). Producers
// fire-and-forget relaxed-agent 2B stores; consumers poll their 8B words and retry any
// ushort still 0xFFFF. Critical path = one-way store visibility + poll hit.
__global__ __launch_bounds__(256, 1)
void lstm_seq(const bf16* __restrict__ Gt, const bf16* __restrict__ whTb,
              const int* __restrict__ lengths, unsigned short* __restrict__ hseq,
              bf16* __restrict__ hcat)
{
    __shared__ __align__(16) unsigned short hl[64 * 520];   // h tile [b][k], pitch 520

    const int bx = blockIdx.x;       // 0..31
    const int d  = bx >> 4;
    const int nb = bx & 15;
    const int u0 = nb * 32;
    const int tid = threadIdx.x;
    const int w    = tid >> 6;
    const int l    = tid & 63;
    const int lo16 = l & 15;
    const int hi4  = l >> 4;
    const int du   = l & 7;
    const int g0   = (l >> 3) & 1;   // gate pair selector: 0 -> {i,f}, 1 -> {j,o}
    const int u    = u0 + w * 8 + du;
    const bool owner = (g0 == 0);

    // ---- persistent B fragments ----
    bf8v bfr[2][16];
#pragma unroll
    for (int nt = 0; nt < 2; ++nt) {
        const bf16* wrow = whTb + (((size_t)d * 512 + u) * 4 + (nt * 2 + g0)) * 512 + hi4 * 8;
#pragma unroll
        for (int kt = 0; kt < 16; ++kt)
            bfr[nt][kt] = *reinterpret_cast<const bf8v*>(wrow + kt * 32);
    }

    int   len_st[16];
    float c_st[16], h_st[16];
#pragma unroll
    for (int mt = 0; mt < 4; ++mt)
#pragma unroll
        for (int rr = 0; rr < 4; ++rr) {
            len_st[mt * 4 + rr] = lengths[mt * 16 + hi4 * 4 + rr];
            c_st[mt * 4 + rr] = 0.f; h_st[mt * 4 + rr] = 0.f;
        }

    for (int t = 0; t < S_LEN; ++t) {
        // ---- issue Gt loads first (overlap with h poll) ----
        f32x4 acc[2][4];
#pragma unroll
        for (int nt = 0; nt < 2; ++nt) {
            const bf16* gtp = Gt + (((size_t)(d * S_LEN + t)) * G4H
                                    + (size_t)(nt * 2 + g0) * 512 + u) * BATCH + hi4 * 4;
#pragma unroll
            for (int mt = 0; mt < 4; ++mt) {
                ull gv = *reinterpret_cast<const ull*>(gtp + mt * 16);
                const unsigned short* gs = reinterpret_cast<const unsigned short*>(&gv);
                f32x4 av;
#pragma unroll
                for (int rr = 0; rr < 4; ++rr) av[rr] = us2f(gs[rr]);
                acc[nt][mt] = av;
            }
        }

        // ---- poll h_t words (8B = 4 consecutive u for one b); retry on 0xFFFF sentinel ----
        const ull* hsrc = reinterpret_cast<const ull*>(
            hseq + (size_t)(t * 2 + d) * BATCH * HID);
        ull pv[32];
        unsigned mask = 0xFFFFFFFFu;
        while (mask) {
#pragma unroll
            for (int i = 0; i < 32; ++i) {
                if (mask & (1u << i)) {
                    ull v = __hip_atomic_load(hsrc + i * 256 + tid,
                                              __ATOMIC_RELAXED, __HIP_MEMORY_SCOPE_AGENT);
                    bool ok = ((v & 0xFFFFull) != 0xFFFFull) &&
                              (((v >> 16) & 0xFFFFull) != 0xFFFFull) &&
                              (((v >> 32) & 0xFFFFull) != 0xFFFFull) &&
                              ((v >> 48) != 0xFFFFull);
                    if (ok) { pv[i] = v; mask &= ~(1u << i); }
                }
            }
            if (mask) __builtin_amdgcn_s_sleep(1);
        }

        __syncthreads();                 // prior step's MFMA reads of hl are done
#pragma unroll
        for (int i = 0; i < 32; ++i) {
            int wd_ = i * 256 + tid;     // 8B word: b = wd>>7, u4 = (wd&127)*4
            *reinterpret_cast<ull*>(&hl[(wd_ >> 7) * 520 + (wd_ & 127) * 4]) = pv[i];
        }
        __syncthreads();

        // ---- MFMA: 16 k-steps x (4 A-frags + 8 mfma) ----
#pragma unroll
        for (int kt = 0; kt < 16; ++kt) {
            bf8v a[4];
#pragma unroll
            for (int mt = 0; mt < 4; ++mt)
                a[mt] = *reinterpret_cast<const bf8v*>(
                    &hl[(mt * 16 + lo16) * 520 + kt * 32 + hi4 * 8]);
#pragma unroll
            for (int nt = 0; nt < 2; ++nt)
#pragma unroll
                for (int mt = 0; mt < 4; ++mt)
                    acc[nt][mt] = __builtin_amdgcn_mfma_f32_16x16x32_bf16(
                        a[mt], bfr[nt][kt], acc[nt][mt], 0, 0, 0);
        }

        // ---- gate merge + pointwise + fire-and-forget h_{t+1} stores ----
        unsigned short* hdst = hseq + (size_t)((t + 1) * 2 + d) * BATCH * HID;
#pragma unroll
        for (int mt = 0; mt < 4; ++mt) {
            f32x4 vif0 = acc[0][mt], vif1 = acc[1][mt];
            float vj[4], vo[4];
#pragma unroll
            for (int rr = 0; rr < 4; ++rr) {
                vj[rr] = __shfl_xor(vif0[rr], 8, 64);
                vo[rr] = __shfl_xor(vif1[rr], 8, 64);
            }
            if (owner) {
#pragma unroll
                for (int rr = 0; rr < 4; ++rr) {
                    int idx = mt * 4 + rr;
                    bool msk = (t < len_st[idx]);
                    float i_ = sigm(vif0[rr]);
                    float j_ = tanhf(vj[rr]);
                    float f_ = sigm(vif1[rr] + 1.0f);   // FORGET_BIAS
                    float o_ = sigm(vo[rr]);
                    float cn = f_ * c_st[idx] + i_ * j_;
                    float hn = o_ * tanhf(cn);
                    if (msk) c_st[idx] = cn;
                    h_st[idx] = msk ? hn : h_st[idx];
                    int b = mt * 16 + hi4 * 4 + rr;
                    union { bf16 v; unsigned short s; } cv;
                    cv.v = __float2bfloat16(h_st[idx]);
                    __hip_atomic_store(hdst + (size_t)b * HID + u, cv.s,
                                       __ATOMIC_RELAXED, __HIP_MEMORY_SCOPE_AGENT);
                }
            }
        }

        // ---- hcat stores (plain, fire-and-forget) ----
        if (owner) {
#pragma unroll
            for (int mt = 0; mt < 4; ++mt)
#pragma unroll
                for (int rr = 0; rr < 4; ++rr) {
                    int idx = mt * 4 + rr;
                    int b = mt * 16 + hi4 * 4 + rr;
                    bool msk = (t < len_st[idx]);
                    int p = (d == 1 && msk) ? (len_st[idx] - 1 - t) : t;
                    hcat[((size_t)p * BATCH + b) * TWOH + (size_t)d * HID + u] =
                        __float2bfloat16(msk ? h_st[idx] : 0.f);
                }
        }
    }
}

// ---------------- dense + softmax: out[b][s][c] ----------------
__global__ __launch_bounds__(256)
void dense_softmax(const bf16* __restrict__ h, const float* __restrict__ wd,
                   const float* __restrict__ bd, float* __restrict__ out)
{
    __shared__ __align__(16) bf16 wdT[NCLS][1032];
    for (int i = threadIdx.x; i < TWOH * NCLS; i += 256) {
        int k = i / NCLS, c = i % NCLS;    // wd[k][c]
        wdT[c][k] = __float2bfloat16(wd[i]);
    }
    __syncthreads();
    const int c  = threadIdx.x & 31;
    const int rl = threadIdx.x >> 5;
#pragma unroll 1
    for (int pass = 0; pass < 8; ++pass) {
        int r = blockIdx.x * 64 + pass * 8 + rl;   // r = s*BATCH + b
        const bf16* hrow = h + (size_t)r * TWOH;
        float acc = -1e30f;
        if (c < NCLS) {
            acc = 0.f;
            for (int k = 0; k < TWOH; k += 8) {
                uint4 hv = *reinterpret_cast<const uint4*>(hrow + k);
                uint4 wv = *reinterpret_cast<const uint4*>(&wdT[c][k]);
                const unsigned short* hs  = reinterpret_cast<const unsigned short*>(&hv);
                const unsigned short* wsp = reinterpret_cast<const unsigned short*>(&wv);
#pragma unroll
                for (int j = 0; j < 8; ++j) acc += us2f(hs[j]) * us2f(wsp[j]);
            }
            acc += bd[c];
        }
        float mx = acc;
#pragma unroll
        for (int o = 16; o; o >>= 1) mx = fmaxf(mx, __shfl_xor(mx, o, 32));
        float e = (c < NCLS) ? __expf(acc - mx) : 0.f;
        float sm = e;
#pragma unroll
        for (int o = 16; o; o >>= 1) sm += __shfl_xor(sm, o, 32);
        if (c < NCLS) {
            int s = r >> 6, b = r & 63;
            out[((size_t)b * S_LEN + s) * NCLS + c] = e / sm;
        }
    }
}

extern "C" void kernel_launch(void* const* d_in, const int* in_sizes, int n_in,
                              void* d_out, int out_size, void* d_ws, size_t ws_size,
                              hipStream_t stream)
{
    const int*   ids   = (const int*)  d_in[0];
    const int*   lens  = (const int*)  d_in[1];
    const float* emb   = (const float*)d_in[2];
    const float* w_fw0 = (const float*)d_in[3];
    const float* b_fw0 = (const float*)d_in[4];
    const float* w_bw0 = (const float*)d_in[5];
    const float* b_bw0 = (const float*)d_in[6];
    const float* w_fw1 = (const float*)d_in[7];
    const float* b_fw1 = (const float*)d_in[8];
    const float* w_bw1 = (const float*)d_in[9];
    const float* b_bw1 = (const float*)d_in[10];
    const float* wd    = (const float*)d_in[11];
    const float* bd    = (const float*)d_in[12];
    float* out = (float*)d_out;

    char* ws = (char*)d_ws;
    size_t off = 0;
    auto alloc = [&](size_t bytes) {
        void* p = ws + off;
        off += (bytes + 255) & ~(size_t)255;
        return p;
    };
    bf16*  x      = (bf16*) alloc((size_t)S_LEN * BATCH * EPAD * 2);
    bf16*  Gt     = (bf16*) alloc((size_t)2 * S_LEN * G4H * BATCH * 2);
    bf16*  hcat0  = (bf16*) alloc((size_t)S_LEN * BATCH * TWOH * 2);
    bf16*  hcat1  = (bf16*) alloc((size_t)S_LEN * BATCH * TWOH * 2);
    bf16*  whTb   = (bf16*) alloc((size_t)4 * 512 * 4 * 512 * 2);
    unsigned short* hseq = (unsigned short*)alloc((size_t)(S_LEN + 1) * 2 * BATCH * HID * 2);

    embed_kernel<<<S_LEN * BATCH, 128, 0, stream>>>(ids, emb, x);
    wtrans_kernel<<<dim3(16, 64, 4), dim3(32, 32), 0, stream>>>(w_fw0, w_bw0, w_fw1, w_bw1, whTb);

    for (int layer = 0; layer < 2; ++layer) {
        // sentinel-init all slots, then zero slot 0 (initial h state)
        hipMemsetAsync(hseq, 0xFF, (size_t)(S_LEN + 1) * 2 * BATCH * HID * 2, stream);
        hipMemsetAsync(hseq, 0x00, (size_t)2 * BATCH * HID * 2, stream);
        const bf16* Ain   = layer ? hcat0 : x;
        int strideA       = layer ? TWOH : EPAD;
        const float* Wf   = layer ? w_fw1 : w_fw0;
        const float* Wb   = layer ? w_bw1 : w_bw0;
        const float* bfp  = layer ? b_fw1 : b_fw0;
        const float* bbp  = layer ? b_bw1 : b_bw0;
        bf16* hcat        = layer ? hcat1 : hcat0;

        gates_gemm<<<dim3(128, 16, 2), 256, 0, stream>>>(Ain, strideA, strideA,
                                                         Wf, Wb, bfp, bbp, lens, Gt);

        const bf16*  Gp   = Gt;
        const bf16*  whp  = whTb + (size_t)layer * 2 * 512 * 4 * 512;
        const int*   lnp  = lens;
        unsigned short* hsp = hseq;
        bf16*        hcp  = hcat;
        void* args[5] = { &Gp, &whp, &lnp, &hsp, &hcp };
        hipLaunchCooperativeKernel(lstm_seq, dim3(32), dim3(256), args, 0, stream);
    }
    dense_softmax<<<256, 256, 0, stream>>>(hcat1, wd, bd, out);

    (void)in_sizes; (void)n_in; (void)out_size; (void)ws_size;
}

// Round 9
// 5004.162 us; speedup vs baseline: 2.0587x; 2.0587x over previous
//
#include <hip/hip_runtime.h>
#include <hip/hip_bf16.h>

#define S_LEN 256
#define BATCH 64
#define EMB   300
#define EPAD  320
#define HID   512
#define G4H   2048
#define NCLS  25
#define TWOH  1024

using bf16 = __hip_bfloat16;
typedef short bf8v __attribute__((ext_vector_type(8)));   // 8 bf16 in 4 VGPRs
typedef float f32x4 __attribute__((ext_vector_type(4)));
typedef unsigned long long ull;

__device__ __forceinline__ float us2f(unsigned short u) {
    union { unsigned int i; float f; } v; v.i = ((unsigned int)u) << 16; return v.f;
}
__device__ __forceinline__ float sigm(float x) { return 1.f / (1.f + __expf(-x)); }

// ---------------- embedding gather: x[t][b][e] (bf16, padded to EPAD) ----------------
__global__ void embed_kernel(const int* __restrict__ ids,
                             const float* __restrict__ emb,
                             bf16* __restrict__ x)
{
    int r = blockIdx.x;            // r = t*BATCH + b
    int t = r >> 6, b = r & 63;
    int id = ids[b * S_LEN + t];
    const float* src = emb + (size_t)id * EMB;
    bf16* dst = x + (size_t)r * EPAD;
    for (int e = threadIdx.x; e < EPAD; e += blockDim.x) {
        float v = (e < EMB) ? src[e] : 0.f;
        dst[e] = __float2bfloat16(v);
    }
}

// ------- transpose recurrent weights to bf16: whTb[wl][u][g][k] = W[D+k][g*512+u] -------
__global__ void wtrans_kernel(const float* __restrict__ w_fw0, const float* __restrict__ w_bw0,
                              const float* __restrict__ w_fw1, const float* __restrict__ w_bw1,
                              bf16* __restrict__ whTb)
{
    __shared__ float tile[32][33];
    int wl = blockIdx.z;
    const float* W; int D;
    if (wl == 0)      { W = w_fw0; D = EMB; }
    else if (wl == 1) { W = w_bw0; D = EMB; }
    else if (wl == 2) { W = w_fw1; D = TWOH; }
    else              { W = w_bw1; D = TWOH; }
    int k0 = blockIdx.x * 32, n0 = blockIdx.y * 32;
    int tx = threadIdx.x, ty = threadIdx.y;
    tile[ty][tx] = W[(size_t)(D + k0 + ty) * G4H + n0 + tx];
    __syncthreads();
    int k = k0 + tx;
    int n = n0 + ty;                  // gate-major column index
    int u = n & 511, g = n >> 9;
    whTb[(((size_t)wl * 512 + u) * 4 + g) * 512 + k] = __float2bfloat16(tile[tx][ty]);
}

// ------- transpose INPUT weights to bf16: wxTb[wl][n][k] = W[k][n], k<D else 0 -------
__global__ void wxtrans_kernel(const float* __restrict__ w_fw0, const float* __restrict__ w_bw0,
                               const float* __restrict__ w_fw1, const float* __restrict__ w_bw1,
                               bf16* __restrict__ wxTb)
{
    __shared__ float tile[32][33];
    int wl = blockIdx.z;
    const float* W; int D;
    if (wl == 0)      { W = w_fw0; D = EMB; }
    else if (wl == 1) { W = w_bw0; D = EMB; }
    else if (wl == 2) { W = w_fw1; D = TWOH; }
    else              { W = w_bw1; D = TWOH; }
    int k0 = blockIdx.x * 32, n0 = blockIdx.y * 32;
    int tx = threadIdx.x, ty = threadIdx.y;
    float v = (k0 + ty < D) ? W[(size_t)(k0 + ty) * G4H + n0 + tx] : 0.f;
    tile[ty][tx] = v;
    __syncthreads();
    wxTb[((size_t)wl * G4H + n0 + ty) * 1024 + k0 + tx] = __float2bfloat16(tile[tx][ty]);
}

// -------- MFMA input-gate GEMM: Gt[z][t][n][b] = (gather(A) @ Wx + bias)^T --------
// 128x128x64 tile, 4 waves (2x2), reg-staged LDS with 16B-chunk XOR swizzle (T2).
__global__ __launch_bounds__(256)
void gates_mfma(const bf16* __restrict__ A, int strideA, int K,
                const bf16* __restrict__ wxTb,
                const float* __restrict__ b_fw, const float* __restrict__ b_bw,
                const int* __restrict__ lengths,
                bf16* __restrict__ Gt)
{
    const int z  = blockIdx.z;
    const int m0 = blockIdx.x * 128;
    const int n0 = blockIdx.y * 128;
    const int tid = threadIdx.x;
    const float* bias = z ? b_bw : b_fw;

    __shared__ __align__(16) unsigned short As[128 * 64];
    __shared__ __align__(16) unsigned short Bs[128 * 64];

    // staging: thread handles 4 chunks (16B) per tile; chunk q = j*256+tid
    const int ca = tid & 7;
    const bf16* srcA[4];
    const bf16* srcB[4];
    int lofs[4];
#pragma unroll
    for (int j = 0; j < 4; ++j) {
        int row = j * 32 + (tid >> 3);
        int r = m0 + row, t = r >> 6, b = r & 63;
        int st = t;
        if (z) { int len = lengths[b]; st = (t < len) ? (len - 1 - t) : t; }
        srcA[j] = A + (size_t)(st * 64 + b) * strideA + ca * 8;
        srcB[j] = wxTb + ((size_t)z * G4H + n0 + row) * 1024 + ca * 8;
        lofs[j] = row * 64 + ((ca ^ (row & 7)) << 3);
    }

    const int l = tid & 63, lo16 = l & 15, hi4 = l >> 4;
    const int wv = tid >> 6, wm = wv >> 1, wn = wv & 1;

    f32x4 acc[4][4];
#pragma unroll
    for (int mi = 0; mi < 4; ++mi)
#pragma unroll
        for (int ni = 0; ni < 4; ++ni)
#pragma unroll
            for (int rr = 0; rr < 4; ++rr) acc[mi][ni][rr] = 0.f;

    uint4 ra[4], rb[4];
#pragma unroll
    for (int j = 0; j < 4; ++j) {
        ra[j] = *reinterpret_cast<const uint4*>(srcA[j]);
        rb[j] = *reinterpret_cast<const uint4*>(srcB[j]);
    }

    const int nk = K >> 6;
    for (int kt = 0; kt < nk; ++kt) {
        __syncthreads();
#pragma unroll
        for (int j = 0; j < 4; ++j) {
            *reinterpret_cast<uint4*>(&As[lofs[j]]) = ra[j];
            *reinterpret_cast<uint4*>(&Bs[lofs[j]]) = rb[j];
        }
        __syncthreads();
        if (kt + 1 < nk) {
#pragma unroll
            for (int j = 0; j < 4; ++j) {
                srcA[j] += 64; srcB[j] += 64;
                ra[j] = *reinterpret_cast<const uint4*>(srcA[j]);
                rb[j] = *reinterpret_cast<const uint4*>(srcB[j]);
            }
        }
#pragma unroll
        for (int ks = 0; ks < 2; ++ks) {
            bf8v af[4], bfv[4];
#pragma unroll
            for (int mi = 0; mi < 4; ++mi) {
                int row = wm * 64 + mi * 16 + lo16;
                int c = ks * 4 + hi4;
                af[mi] = *reinterpret_cast<const bf8v*>(&As[row * 64 + ((c ^ (row & 7)) << 3)]);
            }
#pragma unroll
            for (int ni = 0; ni < 4; ++ni) {
                int row = wn * 64 + ni * 16 + lo16;
                int c = ks * 4 + hi4;
                bfv[ni] = *reinterpret_cast<const bf8v*>(&Bs[row * 64 + ((c ^ (row & 7)) << 3)]);
            }
#pragma unroll
            for (int mi = 0; mi < 4; ++mi)
#pragma unroll
                for (int ni = 0; ni < 4; ++ni)
                    acc[mi][ni] = __builtin_amdgcn_mfma_f32_16x16x32_bf16(
                        af[mi], bfv[ni], acc[mi][ni], 0, 0, 0);
        }
    }

    // epilogue: D row = m0+wm*64+mi*16+hi4*4+rr -> (t, b); col = n0+wn*64+ni*16+lo16
    float bv[4];
#pragma unroll
    for (int ni = 0; ni < 4; ++ni) bv[ni] = bias[n0 + wn * 64 + ni * 16 + lo16];
    const int tt = (m0 >> 6) + wm;
#pragma unroll
    for (int mi = 0; mi < 4; ++mi) {
        int b0 = mi * 16 + hi4 * 4;
#pragma unroll
        for (int ni = 0; ni < 4; ++ni) {
            int n = n0 + wn * 64 + ni * 16 + lo16;
            __align__(8) bf16 tmp[4];
#pragma unroll
            for (int rr = 0; rr < 4; ++rr)
                tmp[rr] = __float2bfloat16(acc[mi][ni][rr] + bv[ni]);
            bf16* gout = Gt + (((size_t)z * S_LEN + tt) * G4H + n) * BATCH + b0;
            *reinterpret_cast<ull*>(gout) = *reinterpret_cast<const ull*>(tmp);
        }
    }
}

// ---------------- persistent MFMA LSTM recurrence (one layer, both dirs) ----------------
// R7 structure (proven): 32 blocks = 2 dirs x 16 u-tiles; weights persistent in VGPR
// B-frags; h staged via LDS; flag barrier (store-once flags, narrow read-only poll).
// R9 change: hl uses 16B-chunk XOR swizzle -> conflict-free (was 8-way, 8.4M conflicts).
__global__ __launch_bounds__(256, 1)
void lstm_seq(const bf16* __restrict__ Gt, const bf16* __restrict__ whTb,
              const int* __restrict__ lengths, unsigned short* __restrict__ hbuf,
              unsigned int* __restrict__ flags, bf16* __restrict__ hcat)
{
    __shared__ __align__(16) unsigned short hl[64 * 512];   // h tile, XOR-swizzled chunks

    const int bx = blockIdx.x;       // 0..31
    const int d  = bx >> 4;
    const int nb = bx & 15;
    const int u0 = nb * 32;
    const int tid = threadIdx.x;
    const int w    = tid >> 6;
    const int l    = tid & 63;
    const int lo16 = l & 15;
    const int hi4  = l >> 4;
    const int du   = l & 7;
    const int g0   = (l >> 3) & 1;   // gate pair selector: 0 -> {i,f}, 1 -> {j,o}
    const int u    = u0 + w * 8 + du;
    const bool owner = (g0 == 0);

    // ---- persistent B fragments ----
    bf8v bfr[2][16];
#pragma unroll
    for (int nt = 0; nt < 2; ++nt) {
        const bf16* wrow = whTb + (((size_t)d * 512 + u) * 4 + (nt * 2 + g0)) * 512 + hi4 * 8;
#pragma unroll
        for (int kt = 0; kt < 16; ++kt)
            bfr[nt][kt] = *reinterpret_cast<const bf8v*>(wrow + kt * 32);
    }

    int   len_st[16];
    float c_st[16], h_st[16];
#pragma unroll
    for (int mt = 0; mt < 4; ++mt)
#pragma unroll
        for (int rr = 0; rr < 4; ++rr) {
            len_st[mt * 4 + rr] = lengths[mt * 16 + hi4 * 4 + rr];
            c_st[mt * 4 + rr] = 0.f; h_st[mt * 4 + rr] = 0.f;
        }

    for (int t = 0; t < S_LEN; ++t) {
        // ---- stage h (64x512 bf16) into LDS via agent-coherent 8B loads ----
        const ull* hsrc = reinterpret_cast<const ull*>(
            hbuf + (size_t)((t & 1) * 2 + d) * BATCH * HID);
        ull pv[32];
#pragma unroll
        for (int i = 0; i < 32; ++i)
            pv[i] = __hip_atomic_load(hsrc + i * 256 + tid,
                                      __ATOMIC_RELAXED, __HIP_MEMORY_SCOPE_AGENT);

        // ---- acc init from Gt[d][t][n][b] (8B = 4 consecutive b) ----
        f32x4 acc[2][4];
#pragma unroll
        for (int nt = 0; nt < 2; ++nt) {
            const bf16* gtp = Gt + (((size_t)(d * S_LEN + t)) * G4H
                                    + (size_t)(nt * 2 + g0) * 512 + u) * BATCH + hi4 * 4;
#pragma unroll
            for (int mt = 0; mt < 4; ++mt) {
                ull gv = *reinterpret_cast<const ull*>(gtp + mt * 16);
                const unsigned short* gs = reinterpret_cast<const unsigned short*>(&gv);
                f32x4 av;
#pragma unroll
                for (int rr = 0; rr < 4; ++rr) av[rr] = us2f(gs[rr]);
                acc[nt][mt] = av;
            }
        }

        __syncthreads();                 // prior step's MFMA reads of hl are done
#pragma unroll
        for (int i = 0; i < 32; ++i) {
            int wd_ = i * 256 + tid;     // 8B word
            int b = wd_ >> 7, r = wd_ & 127;
            int c = r >> 1, half = r & 1;
            *reinterpret_cast<ull*>(&hl[b * 512 + ((c ^ (b & 7)) << 3) + (half << 2)]) = pv[i];
        }
        __syncthreads();

        // ---- MFMA: 16 k-steps x (4 A-frags + 8 mfma), conflict-free swizzled reads ----
#pragma unroll
        for (int kt = 0; kt < 16; ++kt) {
            bf8v a[4];
#pragma unroll
            for (int mt = 0; mt < 4; ++mt) {
                int b = mt * 16 + lo16;
                int c = kt * 4 + hi4;
                a[mt] = *reinterpret_cast<const bf8v*>(
                    &hl[b * 512 + ((c ^ (lo16 & 7)) << 3)]);
            }
#pragma unroll
            for (int nt = 0; nt < 2; ++nt)
#pragma unroll
                for (int mt = 0; mt < 4; ++mt)
                    acc[nt][mt] = __builtin_amdgcn_mfma_f32_16x16x32_bf16(
                        a[mt], bfr[nt][kt], acc[nt][mt], 0, 0, 0);
        }

        // ---- gate merge + pointwise (owner lanes hold i,f; partner l^8 holds j,o) ----
        unsigned short* hdst = hbuf + (size_t)(((t + 1) & 1) * 2 + d) * BATCH * HID;
#pragma unroll
        for (int mt = 0; mt < 4; ++mt) {
            f32x4 vif0 = acc[0][mt], vif1 = acc[1][mt];
            float vj[4], vo[4];
#pragma unroll
            for (int rr = 0; rr < 4; ++rr) {
                vj[rr] = __shfl_xor(vif0[rr], 8, 64);
                vo[rr] = __shfl_xor(vif1[rr], 8, 64);
            }
            if (owner) {
#pragma unroll
                for (int rr = 0; rr < 4; ++rr) {
                    int idx = mt * 4 + rr;
                    bool msk = (t < len_st[idx]);
                    float i_ = sigm(vif0[rr]);
                    float j_ = tanhf(vj[rr]);
                    float f_ = sigm(vif1[rr] + 1.0f);   // FORGET_BIAS
                    float o_ = sigm(vo[rr]);
                    float cn = f_ * c_st[idx] + i_ * j_;
                    float hn = o_ * tanhf(cn);
                    if (msk) c_st[idx] = cn;
                    h_st[idx] = msk ? hn : h_st[idx];
                    int b = mt * 16 + hi4 * 4 + rr;
                    union { bf16 v; unsigned short s; } cv;
                    cv.v = __float2bfloat16(h_st[idx]);
                    __hip_atomic_store(hdst + (size_t)b * HID + u, cv.s,
                                       __ATOMIC_RELAXED, __HIP_MEMORY_SCOPE_AGENT);
                }
            }
        }

        // ---- signal early ----
        asm volatile("s_waitcnt vmcnt(0)" ::: "memory");
        __syncthreads();
        if (tid == 0)
            __hip_atomic_store(&flags[(size_t)t * 32 + d * 16 + nb], 1u,
                               __ATOMIC_RELAXED, __HIP_MEMORY_SCOPE_AGENT);

        // ---- shadow: hcat stores ----
        if (owner) {
#pragma unroll
            for (int mt = 0; mt < 4; ++mt)
#pragma unroll
                for (int rr = 0; rr < 4; ++rr) {
                    int idx = mt * 4 + rr;
                    int b = mt * 16 + hi4 * 4 + rr;
                    bool msk = (t < len_st[idx]);
                    int p = (d == 1 && msk) ? (len_st[idx] - 1 - t) : t;
                    hcat[((size_t)p * BATCH + b) * TWOH + (size_t)d * HID + u] =
                        __float2bfloat16(msk ? h_st[idx] : 0.f);
                }
        }

        // ---- wait: poll this direction's 16 flags (read-only, narrow) ----
        if (tid < 16) {
            const unsigned int* fb = flags + (size_t)t * 32 + d * 16;
            while (__hip_atomic_load(fb + tid, __ATOMIC_RELAXED,
                                     __HIP_MEMORY_SCOPE_AGENT) == 0u)
                __builtin_amdgcn_s_sleep(2);
        }
        __syncthreads();
    }
}

// ---------------- dense + softmax: out[b][s][c] ----------------
__global__ __launch_bounds__(256)
void dense_softmax(const bf16* __restrict__ h, const float* __restrict__ wd,
                   const float* __restrict__ bd, float* __restrict__ out)
{
    __shared__ __align__(16) bf16 wdT[NCLS][1032];
    for (int i = threadIdx.x; i < TWOH * NCLS; i += 256) {
        int k = i / NCLS, c = i % NCLS;    // wd[k][c]
        wdT[c][k] = __float2bfloat16(wd[i]);
    }
    __syncthreads();
    const int c  = threadIdx.x & 31;
    const int rl = threadIdx.x >> 5;
#pragma unroll 1
    for (int pass = 0; pass < 8; ++pass) {
        int r = blockIdx.x * 64 + pass * 8 + rl;   // r = s*BATCH + b
        const bf16* hrow = h + (size_t)r * TWOH;
        float acc = -1e30f;
        if (c < NCLS) {
            acc = 0.f;
            for (int k = 0; k < TWOH; k += 8) {
                uint4 hv = *reinterpret_cast<const uint4*>(hrow + k);
                uint4 wv = *reinterpret_cast<const uint4*>(&wdT[c][k]);
                const unsigned short* hs  = reinterpret_cast<const unsigned short*>(&hv);
                const unsigned short* wsp = reinterpret_cast<const unsigned short*>(&wv);
#pragma unroll
                for (int j = 0; j < 8; ++j) acc += us2f(hs[j]) * us2f(wsp[j]);
            }
            acc += bd[c];
        }
        float mx = acc;
#pragma unroll
        for (int o = 16; o; o >>= 1) mx = fmaxf(mx, __shfl_xor(mx, o, 32));
        float e = (c < NCLS) ? __expf(acc - mx) : 0.f;
        float sm = e;
#pragma unroll
        for (int o = 16; o; o >>= 1) sm += __shfl_xor(sm, o, 32);
        if (c < NCLS) {
            int s = r >> 6, b = r & 63;
            out[((size_t)b * S_LEN + s) * NCLS + c] = e / sm;
        }
    }
}

extern "C" void kernel_launch(void* const* d_in, const int* in_sizes, int n_in,
                              void* d_out, int out_size, void* d_ws, size_t ws_size,
                              hipStream_t stream)
{
    const int*   ids   = (const int*)  d_in[0];
    const int*   lens  = (const int*)  d_in[1];
    const float* emb   = (const float*)d_in[2];
    const float* w_fw0 = (const float*)d_in[3];
    const float* b_fw0 = (const float*)d_in[4];
    const float* w_bw0 = (const float*)d_in[5];
    const float* b_bw0 = (const float*)d_in[6];
    const float* w_fw1 = (const float*)d_in[7];
    const float* b_fw1 = (const float*)d_in[8];
    const float* w_bw1 = (const float*)d_in[9];
    const float* b_bw1 = (const float*)d_in[10];
    const float* wd    = (const float*)d_in[11];
    const float* bd    = (const float*)d_in[12];
    float* out = (float*)d_out;

    char* ws = (char*)d_ws;
    size_t off = 0;
    auto alloc = [&](size_t bytes) {
        void* p = ws + off;
        off += (bytes + 255) & ~(size_t)255;
        return p;
    };
    bf16*  x      = (bf16*) alloc((size_t)S_LEN * BATCH * EPAD * 2);
    bf16*  Gt     = (bf16*) alloc((size_t)2 * S_LEN * G4H * BATCH * 2);
    bf16*  hcat0  = (bf16*) alloc((size_t)S_LEN * BATCH * TWOH * 2);
    bf16*  hcat1  = (bf16*) alloc((size_t)S_LEN * BATCH * TWOH * 2);
    bf16*  whTb   = (bf16*) alloc((size_t)4 * 512 * 4 * 512 * 2);
    bf16*  wxTb   = (bf16*) alloc((size_t)4 * G4H * 1024 * 2);
    unsigned short* hbuf = (unsigned short*)alloc((size_t)2 * 2 * BATCH * HID * 2);
    unsigned int* flags  = (unsigned int*) alloc((size_t)S_LEN * 32 * 4);

    embed_kernel<<<S_LEN * BATCH, 128, 0, stream>>>(ids, emb, x);
    wtrans_kernel<<<dim3(16, 64, 4), dim3(32, 32), 0, stream>>>(w_fw0, w_bw0, w_fw1, w_bw1, whTb);
    wxtrans_kernel<<<dim3(32, 64, 4), dim3(32, 32), 0, stream>>>(w_fw0, w_bw0, w_fw1, w_bw1, wxTb);

    for (int layer = 0; layer < 2; ++layer) {
        hipMemsetAsync(hbuf, 0, (size_t)2 * 2 * BATCH * HID * 2, stream);
        hipMemsetAsync(flags, 0, (size_t)S_LEN * 32 * 4, stream);
        const bf16* Ain   = layer ? hcat0 : x;
        int strideA       = layer ? TWOH : EPAD;
        int K             = layer ? 1024 : EPAD;
        const float* bfp  = layer ? b_fw1 : b_fw0;
        const float* bbp  = layer ? b_bw1 : b_bw0;
        bf16* hcat        = layer ? hcat1 : hcat0;

        gates_mfma<<<dim3(128, 16, 2), 256, 0, stream>>>(
            Ain, strideA, K, wxTb + (size_t)layer * 2 * G4H * 1024,
            bfp, bbp, lens, Gt);

        const bf16*  Gp   = Gt;
        const bf16*  whp  = whTb + (size_t)layer * 2 * 512 * 4 * 512;
        const int*   lnp  = lens;
        unsigned short* hbp = hbuf;
        unsigned int* flp = flags;
        bf16*        hcp  = hcat;
        void* args[6] = { &Gp, &whp, &lnp, &hbp, &flp, &hcp };
        hipLaunchCooperativeKernel(lstm_seq, dim3(32), dim3(256), args, 0, stream);
    }
    dense_softmax<<<256, 256, 0, stream>>>(hcat1, wd, bd, out);

    (void)in_sizes; (void)n_in; (void)out_size; (void)ws_size;
}